// Round 1
// baseline (213.128 us; speedup 1.0000x reference)
//
#include <hip/hip_runtime.h>

#define NODES 128
#define NFEAT 256
#define BATCH 512
#define KTOT  (NODES * NFEAT)   // 32768, stage-3 K
#define SPLIT 64                // stage-3 split-K factor
#define KCH   (KTOT / SPLIT)    // 512 per chunk

typedef __bf16 bf16_t;
typedef bf16_t bf16x4 __attribute__((ext_vector_type(4)));
typedef bf16_t bf16x8 __attribute__((ext_vector_type(8)));
typedef float  f32x4  __attribute__((ext_vector_type(4)));

#define BK    32
#define LDK   40     // bf16 LDS row stride, 32-wide tiles (80B)
#define BK2   64
#define LDK2  72     // bf16 LDS row stride, 64-wide tiles (144B)
#define TILE  128
#define GT    64     // k_fused12 g-tile width (was 128)

// Workgroup barrier WITHOUT the vmcnt(0) drain __syncthreads() emits.
// Only LDS (lgkmcnt) visibility is needed; global prefetch loads stay in flight.
__device__ __forceinline__ void bar() {
    asm volatile("s_waitcnt lgkmcnt(0)\n\ts_barrier" ::: "memory");
}

__device__ __forceinline__ bf16x8 cvt8(const float4 a, const float4 b) {
    bf16x8 t;
    t[0] = (bf16_t)a.x; t[1] = (bf16_t)a.y; t[2] = (bf16_t)a.z; t[3] = (bf16_t)a.w;
    t[4] = (bf16_t)b.x; t[5] = (bf16_t)b.y; t[6] = (bf16_t)b.z; t[7] = (bf16_t)b.w;
    return t;
}

// ---- fp32 128x32 tile: reg-load / LDS-store ----
struct XT { float4 v[4]; };
__device__ __forceinline__ void xload(const float* __restrict__ src, int ld, int k0,
                                      int tid, XT& t) {
#pragma unroll
    for (int i = 0; i < 2; i++) {
        int f = tid + i * 256, r = f >> 2, c = f & 3;
        t.v[2 * i]     = *(const float4*)(src + (size_t)r * ld + k0 + c * 8);
        t.v[2 * i + 1] = *(const float4*)(src + (size_t)r * ld + k0 + c * 8 + 4);
    }
}
__device__ __forceinline__ void xstore(bf16_t* __restrict__ dst, int tid, const XT& t) {
#pragma unroll
    for (int i = 0; i < 2; i++) {
        int f = tid + i * 256, r = f >> 2, c = f & 3;
        *(bf16x8*)(dst + r * LDK + c * 8) = cvt8(t.v[2 * i], t.v[2 * i + 1]);
    }
}

// ---- fp32 128x64 tile (k_out B, fp32 fallback path) ----
struct XT2 { float4 v[8]; };
__device__ __forceinline__ void xload2(const float* __restrict__ src, int ld, int k0,
                                       int tid, XT2& t) {
#pragma unroll
    for (int i = 0; i < 4; i++) {
        int f = tid + i * 256, r = f >> 3, c = f & 7;
        t.v[2 * i]     = *(const float4*)(src + (size_t)r * ld + k0 + c * 8);
        t.v[2 * i + 1] = *(const float4*)(src + (size_t)r * ld + k0 + c * 8 + 4);
    }
}
__device__ __forceinline__ void xstore2(bf16_t* __restrict__ dst, int tid, const XT2& t) {
#pragma unroll
    for (int i = 0; i < 4; i++) {
        int f = tid + i * 256, r = f >> 3, c = f & 7;
        *(bf16x8*)(dst + r * LDK2 + c * 8) = cvt8(t.v[2 * i], t.v[2 * i + 1]);
    }
}

// ---- bf16 128x64 tile (k_out A and bf16 B) ----
struct AT2 { bf16x8 v[4]; };
__device__ __forceinline__ void aload2(const bf16_t* __restrict__ src, int ld, int k0,
                                       int tid, AT2& t) {
#pragma unroll
    for (int i = 0; i < 4; i++) {
        int f = tid + i * 256, r = f >> 3, c = f & 7;
        t.v[i] = *(const bf16x8*)(src + (size_t)r * ld + k0 + c * 8);
    }
}
__device__ __forceinline__ void astore2(bf16_t* __restrict__ dst, int tid, const AT2& t) {
#pragma unroll
    for (int i = 0; i < 4; i++) {
        int f = tid + i * 256, r = f >> 3, c = f & 7;
        *(bf16x8*)(dst + r * LDK2 + c * 8) = t.v[i];
    }
}

// ---- pre-transpose gcn_w[k][g] -> wT[g][k] bf16 ----
__global__ __launch_bounds__(256)
void k_wt(const float* __restrict__ w, bf16_t* __restrict__ wT) {
    const int g0 = blockIdx.x * 4;
    const int k  = threadIdx.x;
    const float4 v = *(const float4*)(w + (size_t)k * NFEAT + g0);
    wT[(size_t)(g0 + 0) * NFEAT + k] = (bf16_t)v.x;
    wT[(size_t)(g0 + 1) * NFEAT + k] = (bf16_t)v.y;
    wT[(size_t)(g0 + 2) * NFEAT + k] = (bf16_t)v.z;
    wT[(size_t)(g0 + 3) * NFEAT + k] = (bf16_t)v.w;
}

// ---- pre-convert fc_w fp32 -> bf16 (streaming, ~50 MB) ----
__global__ __launch_bounds__(256)
void k_fwt(const float* __restrict__ w, bf16_t* __restrict__ wb) {
    const size_t i = ((size_t)blockIdx.x * 256 + threadIdx.x) * 8;
    const float4 a = *(const float4*)(w + i);
    const float4 b = *(const float4*)(w + i + 4);
    *(bf16x8*)(wb + i) = cvt8(a, b);
}

// ---- fused stages 1+2: 64-wide g tiles, 4 blk/CU, XCD-swizzled grid ----
// LDS 36.9 KB -> 4 blocks/CU; 2048 blocks = exactly 2 full rounds at 16 waves/CU
// (previous 128-g version: 52.4 KB -> 3 blk/CU, 1024 blocks = rounds of 3 then 1,
//  time-avg occupancy 25% -- measured 22%, HBM stuck at 2.5 TB/s).
__global__ __launch_bounds__(256, 4)
void k_fused12(const float* __restrict__ x, const float* __restrict__ adj,
               const bf16_t* __restrict__ wT, const float* __restrict__ gcn_b,
               bf16_t* __restrict__ mid) {
    __shared__ __align__(16) bf16_t As[2][TILE * LDK];  // 2 x 10 KB
    __shared__ __align__(16) bf16_t Sb[GT * 128];       // 16 KB, XOR-swizzled
    // XCD swizzle: the 4 g-tiles of one batch land on the SAME XCD, adjacent
    // in its queue -> x/adj re-reads stay L2 hits despite 4-way re-issue.
    const int id  = blockIdx.y * 4 + blockIdx.x;        // linear dispatch id
    const int xcd = id & 7, jj = id >> 3;
    const int b   = (xcd << 6) | (jj >> 2);             // bijective for 2048 ids
    const int n0  = (jj & 3) * GT;                      // g-tile base
    const int tid = threadIdx.x;
    const int lane = tid & 63, w = tid >> 6, wm = w & 1, wn = w >> 1;
    const int l15 = lane & 15, q = lane >> 4;
    const float* xb   = x   + (size_t)b * NODES * NFEAT;
    const float* adjb = adj + (size_t)b * NODES * NODES;

    const bf16_t* wrow[2];
#pragma unroll
    for (int j = 0; j < 2; j++)
        wrow[j] = wT + (size_t)(n0 + wn * 32 + j * 16 + l15) * NFEAT + q * 8;

    // ---- stage 1: S = x[b] @ W  (K=256, 8 iters, 1 barrier/iter) ----
    f32x4 acc[4][2] = {};
    {
        XT r[3];
        xload(xb, NFEAT, 0 * BK, tid, r[0]);
        xload(xb, NFEAT, 1 * BK, tid, r[1]);
        xload(xb, NFEAT, 2 * BK, tid, r[2]);
        xstore(As[0], tid, r[0]);       // tile 0 -> buf 0
        bar();
#pragma unroll
        for (int k = 0; k < 8; k++) {
            if (k + 3 < 8) xload(xb, NFEAT, (k + 3) * BK, tid, r[k % 3]);  // dist-3
            bf16x8 bcur[2];
#pragma unroll
            for (int j = 0; j < 2; j++) bcur[j] = *(const bf16x8*)(wrow[j] + k * BK);
            bf16x8 a[4];
#pragma unroll
            for (int i = 0; i < 4; i++)
                a[i] = *(const bf16x8*)(&As[k & 1][(wm * 64 + i * 16 + l15) * LDK + q * 8]);
#pragma unroll
            for (int i = 0; i < 4; i++)
#pragma unroll
                for (int j = 0; j < 2; j++)
                    acc[i][j] = __builtin_amdgcn_mfma_f32_16x16x32_bf16(a[i], bcur[j], acc[i][j], 0, 0, 0);
            if (k + 1 < 8) xstore(As[(k + 1) & 1], tid, r[(k + 1) % 3]); // data 2 iters old
            bar();
        }
    }

    // preload adj tiles 0..2 while writing Sb
    XT r[3];
    xload(adjb, NODES, 0 * BK, tid, r[0]);
    xload(adjb, NODES, 1 * BK, tid, r[1]);
    xload(adjb, NODES, 2 * BK, tid, r[2]);
    // S -> Sb[g][m], XOR chunk swizzle: slot = (m>>3) ^ (g&15)
#pragma unroll
    for (int i = 0; i < 4; i++)
#pragma unroll
        for (int j = 0; j < 2; j++)
#pragma unroll
            for (int rr = 0; rr < 4; rr++) {
                int m = wm * 64 + i * 16 + q * 4 + rr;
                int g = wn * 32 + j * 16 + l15;
                int slot = (m >> 3) ^ (g & 15);
                Sb[g * 128 + slot * 8 + (m & 7)] = (bf16_t)acc[i][j][rr];
            }
    bar();                              // Sb visible; stage-1 As reads done
    xstore(As[0], tid, r[0]);
    bar();

    // ---- stage 2: mid = adj[b] @ S  (K=128, 4 iters, 1 barrier/iter) ----
    f32x4 acc2[4][2] = {};
#pragma unroll
    for (int k = 0; k < 4; k++) {
        if (k + 3 < 4) xload(adjb, NODES, (k + 3) * BK, tid, r[k % 3]);
        bf16x8 a[4], bb[2];
#pragma unroll
        for (int i = 0; i < 4; i++)
            a[i] = *(const bf16x8*)(&As[k & 1][(wm * 64 + i * 16 + l15) * LDK + q * 8]);
#pragma unroll
        for (int j = 0; j < 2; j++) {
            int R = wn * 32 + j * 16 + l15;
            int slot = (k * 4 + q) ^ (R & 15);
            bb[j] = *(const bf16x8*)(&Sb[R * 128 + slot * 8]);
        }
#pragma unroll
        for (int i = 0; i < 4; i++)
#pragma unroll
            for (int j = 0; j < 2; j++)
                acc2[i][j] = __builtin_amdgcn_mfma_f32_16x16x32_bf16(a[i], bb[j], acc2[i][j], 0, 0, 0);
        if (k + 1 < 4) xstore(As[(k + 1) & 1], tid, r[(k + 1) % 3]);
        bar();
    }
    // epilogue: + gcn_b -> mid[b][node][g]
    bf16_t* outb = mid + (size_t)b * NODES * NFEAT;
#pragma unroll
    for (int j = 0; j < 2; j++) {
        int g = n0 + wn * 32 + j * 16 + l15;
        float bias = gcn_b[g];
#pragma unroll
        for (int i = 0; i < 4; i++)
#pragma unroll
            for (int rr = 0; rr < 4; rr++) {
                int node = wm * 64 + i * 16 + q * 4 + rr;
                outb[(size_t)node * NFEAT + g] = (bf16_t)(acc2[i][j][rr] + bias);
            }
    }
}

// ---- stage 3 (bf16 B): split-K=64, BK=64, single-barrier dbuf ----
__global__ __launch_bounds__(256, 2)
void k_out_bf(const bf16_t* __restrict__ flat, const bf16_t* __restrict__ fcwb,
              bf16_t* __restrict__ part) {
    __shared__ __align__(16) bf16_t As[2][TILE * LDK2];  // 2 x 18.4 KB
    __shared__ __align__(16) bf16_t Bs[2][TILE * LDK2];  // 2 x 18.4 KB
    const int m0 = blockIdx.x * TILE;
    const int n0 = blockIdx.y * TILE;
    const int kb = blockIdx.z * KCH;     // 8 iters of BK2
    const int tid = threadIdx.x;
    const int lane = tid & 63, w = tid >> 6, wm = w & 1, wn = w >> 1;
    const int l15 = lane & 15, q = lane >> 4;
    f32x4 acc[4][4] = {};
    const bf16_t* fa = flat + (size_t)m0 * KTOT;
    const bf16_t* fb = fcwb + (size_t)n0 * KTOT;

    AT2 ra[3], rb[2];
    aload2(fa, KTOT, kb + 0 * BK2, tid, ra[0]);
    aload2(fb, KTOT, kb + 0 * BK2, tid, rb[0]);
    aload2(fa, KTOT, kb + 1 * BK2, tid, ra[1]);
    aload2(fb, KTOT, kb + 1 * BK2, tid, rb[1]);
    aload2(fa, KTOT, kb + 2 * BK2, tid, ra[2]);
    astore2(As[0], tid, ra[0]);
    astore2(Bs[0], tid, rb[0]);
    bar();
#pragma unroll
    for (int k = 0; k < 8; k++) {
        if (k + 3 < 8) aload2(fa, KTOT, kb + (k + 3) * BK2, tid, ra[k % 3]);   // A dist-3
        if (k + 2 < 8) aload2(fb, KTOT, kb + (k + 2) * BK2, tid, rb[k & 1]);   // B dist-2
#pragma unroll
        for (int kk = 0; kk < BK2; kk += BK) {
            bf16x8 a[4], bbf[4];
#pragma unroll
            for (int i = 0; i < 4; i++)
                a[i] = *(const bf16x8*)(&As[k & 1][(wm * 64 + i * 16 + l15) * LDK2 + kk + q * 8]);
#pragma unroll
            for (int j = 0; j < 4; j++)
                bbf[j] = *(const bf16x8*)(&Bs[k & 1][(wn * 64 + j * 16 + l15) * LDK2 + kk + q * 8]);
#pragma unroll
            for (int i = 0; i < 4; i++)
#pragma unroll
                for (int j = 0; j < 4; j++)
                    acc[i][j] = __builtin_amdgcn_mfma_f32_16x16x32_bf16(a[i], bbf[j], acc[i][j], 0, 0, 0);
        }
        if (k + 1 < 8) {
            astore2(As[(k + 1) & 1], tid, ra[(k + 1) % 3]);
            astore2(Bs[(k + 1) & 1], tid, rb[(k + 1) & 1]);
        }
        bar();
    }
    bf16_t* pb = part + (size_t)blockIdx.z * BATCH * NFEAT;
#pragma unroll
    for (int i = 0; i < 4; i++)
#pragma unroll
        for (int j = 0; j < 4; j++)
#pragma unroll
            for (int r = 0; r < 4; r++) {
                int bt_ = m0 + wm * 64 + i * 16 + q * 4 + r;
                int o   = n0 + wn * 64 + j * 16 + l15;
                pb[(size_t)bt_ * NFEAT + o] = (bf16_t)acc[i][j][r];
            }
}

// ---- stage 3 (fp32 B fallback, used only if ws too small for fcwb) ----
__global__ __launch_bounds__(256, 2)
void k_out(const bf16_t* __restrict__ flat, const float* __restrict__ fcw,
           bf16_t* __restrict__ part) {
    __shared__ __align__(16) bf16_t As[2][TILE * LDK2];
    __shared__ __align__(16) bf16_t Bs[2][TILE * LDK2];
    const int m0 = blockIdx.x * TILE;
    const int n0 = blockIdx.y * TILE;
    const int kb = blockIdx.z * KCH;
    const int tid = threadIdx.x;
    const int lane = tid & 63, w = tid >> 6, wm = w & 1, wn = w >> 1;
    const int l15 = lane & 15, q = lane >> 4;
    f32x4 acc[4][4] = {};
    const bf16_t* fa = flat + (size_t)m0 * KTOT;
    const float*  fb = fcw + (size_t)n0 * KTOT;

    AT2 ra[3]; XT2 rb[2];
    aload2(fa, KTOT, kb + 0 * BK2, tid, ra[0]);
    xload2(fb, KTOT, kb + 0 * BK2, tid, rb[0]);
    aload2(fa, KTOT, kb + 1 * BK2, tid, ra[1]);
    xload2(fb, KTOT, kb + 1 * BK2, tid, rb[1]);
    aload2(fa, KTOT, kb + 2 * BK2, tid, ra[2]);
    astore2(As[0], tid, ra[0]);
    xstore2(Bs[0], tid, rb[0]);
    bar();
#pragma unroll
    for (int k = 0; k < 8; k++) {
        if (k + 3 < 8) aload2(fa, KTOT, kb + (k + 3) * BK2, tid, ra[k % 3]);
        if (k + 2 < 8) xload2(fb, KTOT, kb + (k + 2) * BK2, tid, rb[k & 1]);
#pragma unroll
        for (int kk = 0; kk < BK2; kk += BK) {
            bf16x8 a[4], bbf[4];
#pragma unroll
            for (int i = 0; i < 4; i++)
                a[i] = *(const bf16x8*)(&As[k & 1][(wm * 64 + i * 16 + l15) * LDK2 + kk + q * 8]);
#pragma unroll
            for (int j = 0; j < 4; j++)
                bbf[j] = *(const bf16x8*)(&Bs[k & 1][(wn * 64 + j * 16 + l15) * LDK2 + kk + q * 8]);
#pragma unroll
            for (int i = 0; i < 4; i++)
#pragma unroll
                for (int j = 0; j < 4; j++)
                    acc[i][j] = __builtin_amdgcn_mfma_f32_16x16x32_bf16(a[i], bbf[j], acc[i][j], 0, 0, 0);
        }
        if (k + 1 < 8) {
            astore2(As[(k + 1) & 1], tid, ra[(k + 1) % 3]);
            xstore2(Bs[(k + 1) & 1], tid, rb[(k + 1) & 1]);
        }
        bar();
    }
    bf16_t* pb = part + (size_t)blockIdx.z * BATCH * NFEAT;
#pragma unroll
    for (int i = 0; i < 4; i++)
#pragma unroll
        for (int j = 0; j < 4; j++)
#pragma unroll
            for (int r = 0; r < 4; r++) {
                int bt_ = m0 + wm * 64 + i * 16 + q * 4 + r;
                int o   = n0 + wn * 64 + j * 16 + l15;
                pb[(size_t)bt_ * NFEAT + o] = (bf16_t)acc[i][j][r];
            }
}

// ---- stage 4: reduce bf16 partials + fc_b -> slots 0,2; x[:,0,:] -> slot 1 ----
__global__ __launch_bounds__(256)
void k_reduce(const bf16_t* __restrict__ part, const float* __restrict__ fc_b,
              const float* __restrict__ x, float* __restrict__ out) {
    const int g4 = (blockIdx.x * 256 + threadIdx.x) * 4;   // 128 blocks
    const int o = g4 & (NFEAT - 1), b = g4 >> 8;
    float s[4];
    const float4 c0 = *(const float4*)(fc_b + o);
    s[0] = c0.x; s[1] = c0.y; s[2] = c0.z; s[3] = c0.w;
#pragma unroll 8
    for (int i = 0; i < SPLIT; i++) {
        bf16x4 p = *(const bf16x4*)(part + (size_t)i * BATCH * NFEAT + g4);
#pragma unroll
        for (int j = 0; j < 4; j++) s[j] += (float)p[j];
    }
    float4 o0 = make_float4(s[0], s[1], s[2], s[3]);
    *(float4*)(out + g4) = o0;
    *(float4*)(out + 2 * BATCH * NFEAT + g4) = o0;
    *(float4*)(out + BATCH * NFEAT + g4) = *(const float4*)(x + (size_t)b * NODES * NFEAT + o);
}

extern "C" void kernel_launch(void* const* d_in, const int* in_sizes, int n_in,
                              void* d_out, int out_size, void* d_ws, size_t ws_size,
                              hipStream_t stream) {
    const float* x     = (const float*)d_in[0];
    const float* adj   = (const float*)d_in[1];
    const float* gcn_w = (const float*)d_in[2];
    const float* gcn_b = (const float*)d_in[3];
    const float* fc_w  = (const float*)d_in[4];
    const float* fc_b  = (const float*)d_in[5];
    float* out = (float*)d_out;

    // ws: wT 128KB | mid 33.5MB | part (bf16) 16.8MB | fcwb (bf16) 16.8MB => ~67.2 MB
    const size_t midB  = (size_t)BATCH * NODES * NFEAT * 2;
    const size_t partB = (size_t)SPLIT * BATCH * NFEAT * 2;
    const size_t fcwB  = (size_t)NFEAT * KTOT * 2;
    bf16_t* wT   = (bf16_t*)d_ws;
    bf16_t* mid  = (bf16_t*)((char*)d_ws + 131072);
    bf16_t* part = (bf16_t*)((char*)d_ws + 131072 + midB);
    bf16_t* fcwb = (bf16_t*)((char*)d_ws + 131072 + midB + partB);
    const bool cv = ws_size >= 131072 + midB + partB + fcwB;

    k_wt     <<<dim3(64), dim3(256), 0, stream>>>(gcn_w, wT);
    if (cv)
        k_fwt<<<dim3(4096), dim3(256), 0, stream>>>(fc_w, fcwb);
    k_fused12<<<dim3(4, BATCH), dim3(256), 0, stream>>>(x, adj, wT, gcn_b, mid);
    if (cv)
        k_out_bf<<<dim3(4, 2, SPLIT), dim3(256), 0, stream>>>(mid, fcwb, part);
    else
        k_out   <<<dim3(4, 2, SPLIT), dim3(256), 0, stream>>>(mid, fc_w, part);
    k_reduce <<<dim3(128), dim3(256), 0, stream>>>(part, fc_b, x, out);
}